// Round 1
// baseline (16826.303 us; speedup 1.0000x reference)
//
#include <hip/hip_runtime.h>
#include <hip/hip_bf16.h>
#include <math.h>

#define B_  2
#define S_  1024
#define D_  1024
#define H_  16
#define HD_ 64
#define L_  8
#define FF_ 4096
#define V_  50257
#define M_  (B_ * S_)     // 2048 token rows
#define EPS_ 1e-5f

// ---------------------------------------------------------------- embed
// x[m,d] = tok_emb[idx[m], d] + pos_emb[m % S, d]
__global__ __launch_bounds__(256) void embed_kernel(
    const int* __restrict__ idx, const float* __restrict__ tok,
    const float* __restrict__ pos, float* __restrict__ x) {
  int i = blockIdx.x * 256 + threadIdx.x;        // over M_*D_/4 float4s
  int m = i >> 8;                                 // 256 float4 per row
  int d4 = i & 255;
  int s = m & (S_ - 1);
  int t = idx[m];
  float4 tv = ((const float4*)(tok + (size_t)t * D_))[d4];
  float4 pv = ((const float4*)(pos + (size_t)s * D_))[d4];
  float4 o;
  o.x = tv.x + pv.x; o.y = tv.y + pv.y; o.z = tv.z + pv.z; o.w = tv.w + pv.w;
  ((float4*)(x + (size_t)m * D_))[d4] = o;
}

// ---------------------------------------------------------------- layernorm
__device__ __forceinline__ float block_sum256(float v, float* red) {
  #pragma unroll
  for (int o = 32; o > 0; o >>= 1) v += __shfl_xor(v, o);
  int w = threadIdx.x >> 6;
  __syncthreads();                  // protect red from previous use
  if ((threadIdx.x & 63) == 0) red[w] = v;
  __syncthreads();
  return red[0] + red[1] + red[2] + red[3];
}

__global__ __launch_bounds__(256) void layernorm_kernel(
    const float* __restrict__ x, const float* __restrict__ sc,
    const float* __restrict__ bi, float* __restrict__ out) {
  __shared__ float red[4];
  int row = blockIdx.x;
  const float4* xr = (const float4*)(x + (size_t)row * D_);
  float4 v = xr[threadIdx.x];                      // 4 elems / thread, D=1024
  float sum = block_sum256(v.x + v.y + v.z + v.w, red);
  float mu = sum * (1.0f / D_);
  float dx = v.x - mu, dy = v.y - mu, dz = v.z - mu, dw = v.w - mu;
  float sq = block_sum256(dx*dx + dy*dy + dz*dz + dw*dw, red);
  float r = rsqrtf(sq * (1.0f / D_) + EPS_);
  int c = threadIdx.x * 4;
  float4 s4 = *(const float4*)(sc + c);
  float4 b4 = *(const float4*)(bi + c);
  float4 o;
  o.x = dx * r * s4.x + b4.x;
  o.y = dy * r * s4.y + b4.y;
  o.z = dz * r * s4.z + b4.z;
  o.w = dw * r * s4.w + b4.w;
  ((float4*)(out + (size_t)row * D_))[threadIdx.x] = o;
}

// ---------------------------------------------------------------- GEMM
// C[M,N] = A[M,K] * Bw[N,K]^T  (+bias[N]) (+relu) (+res[M,N])
// 64x64 tile, BK=16, 256 threads, 4x4 per thread. M must be multiple of 64.
template<bool BIAS, bool RELU, bool RES>
__global__ __launch_bounds__(256) void gemm_bt(
    const float* __restrict__ A, const float* __restrict__ Bw,
    const float* __restrict__ bias, const float* __restrict__ res,
    float* __restrict__ C, int M, int N, int K) {
  __shared__ float As[16][68];   // [k][m], pad 68 keeps float4 align + no conflicts
  __shared__ float Bs[16][68];   // [k][n]
  const int tid = threadIdx.x;
  const int bm = blockIdx.y * 64, bn = blockIdx.x * 64;
  const int tx = tid & 15, ty = tid >> 4;
  const int lr = tid >> 2;            // 0..63: tile row loaded by this thread
  const int lc = (tid & 3) << 2;      // 0,4,8,12: k-offset loaded (float4)
  float acc[4][4] = {};
  const int gm = bm + lr;
  const int gn = bn + lr;
  const float* Arow = A + (size_t)gm * K + lc;
  const bool bok = (gn < N);
  const float* Brow = Bw + (size_t)(bok ? gn : 0) * K + lc;

  for (int k0 = 0; k0 < K; k0 += 16) {
    float4 av = *(const float4*)(Arow + k0);
    float4 bv = bok ? *(const float4*)(Brow + k0) : make_float4(0.f, 0.f, 0.f, 0.f);
    __syncthreads();
    As[lc + 0][lr] = av.x; As[lc + 1][lr] = av.y;
    As[lc + 2][lr] = av.z; As[lc + 3][lr] = av.w;
    Bs[lc + 0][lr] = bv.x; Bs[lc + 1][lr] = bv.y;
    Bs[lc + 2][lr] = bv.z; Bs[lc + 3][lr] = bv.w;
    __syncthreads();
    #pragma unroll
    for (int kk = 0; kk < 16; ++kk) {
      float4 a4 = *(const float4*)(&As[kk][ty << 2]);
      float4 b4 = *(const float4*)(&Bs[kk][tx << 2]);
      float av_[4] = {a4.x, a4.y, a4.z, a4.w};
      float bv_[4] = {b4.x, b4.y, b4.z, b4.w};
      #pragma unroll
      for (int i = 0; i < 4; ++i)
        #pragma unroll
        for (int j = 0; j < 4; ++j)
          acc[i][j] += av_[i] * bv_[j];
    }
  }
  #pragma unroll
  for (int i = 0; i < 4; ++i) {
    int row = bm + (ty << 2) + i;
    #pragma unroll
    for (int j = 0; j < 4; ++j) {
      int col = bn + (tx << 2) + j;
      if (col < N) {
        float v = acc[i][j];
        if (BIAS) v += bias[col];
        if (RELU) v = fmaxf(v, 0.f);
        if (RES)  v += res[(size_t)row * N + col];
        C[(size_t)row * N + col] = v;
      }
    }
  }
}

// ---------------------------------------------------------------- attention
// One wave per (b, h, q-row). Online softmax, per-lane key-strided, LDS merge.
// qkv layout: [M, 3D], head h at col h*192: q=+0, k=+64, v=+128.
__global__ __launch_bounds__(64) void attn_kernel(
    const float* __restrict__ qkv, float* __restrict__ out) {
  const int q = blockIdx.x, h = blockIdx.y, b = blockIdx.z;
  const int lane = threadIdx.x;
  __shared__ float qs[HD_];
  __shared__ float accs[64][HD_ + 1];
  const size_t base = (size_t)(b * S_) * (3 * D_) + h * (3 * HD_);
  qs[lane] = qkv[base + (size_t)q * (3 * D_) + lane] * 0.125f;  // fold 1/sqrt(64)
  __syncthreads();
  float m = -INFINITY, ssum = 0.f;
  float acc[HD_];
  #pragma unroll
  for (int d = 0; d < HD_; ++d) acc[d] = 0.f;

  for (int k = lane; k <= q; k += 64) {
    const float* kp = qkv + base + (size_t)k * (3 * D_) + HD_;
    float s = 0.f;
    #pragma unroll
    for (int d = 0; d < HD_; d += 4) {
      float4 kv = *(const float4*)(kp + d);
      s += qs[d] * kv.x + qs[d + 1] * kv.y + qs[d + 2] * kv.z + qs[d + 3] * kv.w;
    }
    float nm = fmaxf(m, s);
    float corr = __expf(m - nm);     // m=-inf first iter -> corr=0, no NaN (nm=s finite)
    float p = __expf(s - nm);
    m = nm;
    ssum = ssum * corr + p;
    const float* vp = kp + HD_;
    #pragma unroll
    for (int d = 0; d < HD_; d += 4) {
      float4 vv = *(const float4*)(vp + d);
      acc[d + 0] = acc[d + 0] * corr + p * vv.x;
      acc[d + 1] = acc[d + 1] * corr + p * vv.y;
      acc[d + 2] = acc[d + 2] * corr + p * vv.z;
      acc[d + 3] = acc[d + 3] * corr + p * vv.w;
    }
  }
  // merge the 64 per-lane partial softmaxes
  float gm = m;
  #pragma unroll
  for (int o = 32; o > 0; o >>= 1) gm = fmaxf(gm, __shfl_xor(gm, o));
  float corr = __expf(m - gm);       // lanes with no keys: exp(-inf)=0
  float ss = ssum * corr;
  #pragma unroll
  for (int o = 32; o > 0; o >>= 1) ss += __shfl_xor(ss, o);
  #pragma unroll
  for (int d = 0; d < HD_; ++d) accs[lane][d] = acc[d] * corr;
  __syncthreads();
  float o = 0.f;
  #pragma unroll
  for (int l = 0; l < 64; ++l) o += accs[l][lane];   // bank-clean: (65l+lane)%32
  out[(size_t)(b * S_ + q) * D_ + h * HD_ + lane] = o / ss;
}

// ---------------------------------------------------------------- launch
extern "C" void kernel_launch(void* const* d_in, const int* in_sizes, int n_in,
                              void* d_out, int out_size, void* d_ws, size_t ws_size,
                              hipStream_t stream) {
  const int*   idx    = (const int*)d_in[0];
  const float* tok    = (const float*)d_in[1];
  const float* pos    = (const float*)d_in[2];
  const float* qkv_w  = (const float*)d_in[3];
  const float* proj_w = (const float*)d_in[4];
  const float* proj_b = (const float*)d_in[5];
  const float* ln1_s  = (const float*)d_in[6];
  const float* ln1_b  = (const float*)d_in[7];
  const float* fc1_w  = (const float*)d_in[8];
  const float* fc1_b  = (const float*)d_in[9];
  const float* fc2_w  = (const float*)d_in[10];
  const float* fc2_b  = (const float*)d_in[11];
  const float* ln2_s  = (const float*)d_in[12];
  const float* ln2_b  = (const float*)d_in[13];
  const float* lnf_s  = (const float*)d_in[14];
  const float* lnf_b  = (const float*)d_in[15];
  const float* head_w = (const float*)d_in[16];
  const float* head_b = (const float*)d_in[17];
  float* out = (float*)d_out;

  // workspace layout (floats): x | h | attn | qkv | ff  = 80 MiB total
  float* ws   = (float*)d_ws;
  float* x    = ws;
  float* hbuf = x    + (size_t)M_ * D_;
  float* attn = hbuf + (size_t)M_ * D_;
  float* qkv  = attn + (size_t)M_ * D_;
  float* ff   = qkv  + (size_t)M_ * 3 * D_;

  embed_kernel<<<M_ * D_ / 4 / 256, 256, 0, stream>>>(idx, tok, pos, x);

  for (int l = 0; l < L_; ++l) {
    layernorm_kernel<<<M_, 256, 0, stream>>>(x, ln1_s + l * D_, ln1_b + l * D_, hbuf);
    gemm_bt<false, false, false><<<dim3(3 * D_ / 64, M_ / 64), 256, 0, stream>>>(
        hbuf, qkv_w + (size_t)l * 3 * D_ * D_, nullptr, nullptr, qkv, M_, 3 * D_, D_);
    attn_kernel<<<dim3(S_, H_, B_), 64, 0, stream>>>(qkv, attn);
    gemm_bt<true, false, true><<<dim3(D_ / 64, M_ / 64), 256, 0, stream>>>(
        attn, proj_w + (size_t)l * D_ * D_, proj_b + l * D_, x, x, M_, D_, D_);
    layernorm_kernel<<<M_, 256, 0, stream>>>(x, ln2_s + l * D_, ln2_b + l * D_, hbuf);
    gemm_bt<true, true, false><<<dim3(FF_ / 64, M_ / 64), 256, 0, stream>>>(
        hbuf, fc1_w + (size_t)l * FF_ * D_, fc1_b + l * FF_, nullptr, ff, M_, FF_, D_);
    gemm_bt<true, false, true><<<dim3(D_ / 64, M_ / 64), 256, 0, stream>>>(
        ff, fc2_w + (size_t)l * D_ * FF_, fc2_b + l * D_, x, x, M_, D_, FF_);
  }
  layernorm_kernel<<<M_, 256, 0, stream>>>(x, lnf_s, lnf_b, hbuf);
  gemm_bt<true, false, false><<<dim3((V_ + 63) / 64, M_ / 64), 256, 0, stream>>>(
      hbuf, head_w, head_b, nullptr, out, M_, V_, D_);
}

// Round 2
// 9428.765 us; speedup vs baseline: 1.7846x; 1.7846x over previous
//
#include <hip/hip_runtime.h>
#include <hip/hip_bf16.h>
#include <math.h>

#define B_  2
#define S_  1024
#define D_  1024
#define H_  16
#define HD_ 64
#define L_  8
#define FF_ 4096
#define V_  50257
#define M_  (B_ * S_)     // 2048 token rows
#define EPS_ 1e-5f

typedef __attribute__((ext_vector_type(8))) short short8;   // 8 bf16 (4 VGPRs)
typedef __attribute__((ext_vector_type(4))) float f32x4;    // MFMA accum

__device__ __forceinline__ unsigned short f2bf(float f) {
  union { float f; uint32_t u; } c; c.f = f;
  uint32_t r = (c.u + 0x7FFFu + ((c.u >> 16) & 1u)) >> 16;  // RNE
  return (unsigned short)r;
}
__device__ __forceinline__ float b2f(unsigned short u) {
  union { uint32_t u; float f; } c; c.u = ((uint32_t)u) << 16;
  return c.f;
}
__device__ __forceinline__ void gll16(const unsigned short* g, unsigned short* lds) {
  __builtin_amdgcn_global_load_lds(
      (const __attribute__((address_space(1))) void*)g,
      (__attribute__((address_space(3))) void*)lds, 16, 0, 0);
}

// ---------------------------------------------------------------- embed (fp32 x)
__global__ __launch_bounds__(256) void embed_kernel(
    const int* __restrict__ idx, const float* __restrict__ tok,
    const float* __restrict__ pos, float* __restrict__ x) {
  int i = blockIdx.x * 256 + threadIdx.x;
  int m = i >> 8;
  int d4 = i & 255;
  int s = m & (S_ - 1);
  int t = idx[m];
  float4 tv = ((const float4*)(tok + (size_t)t * D_))[d4];
  float4 pv = ((const float4*)(pos + (size_t)s * D_))[d4];
  float4 o;
  o.x = tv.x + pv.x; o.y = tv.y + pv.y; o.z = tv.z + pv.z; o.w = tv.w + pv.w;
  ((float4*)(x + (size_t)m * D_))[d4] = o;
}

// ---------------------------------------------------------------- f32 -> bf16
__global__ __launch_bounds__(256) void cvt_bf16_kernel(
    const float* __restrict__ in, unsigned short* __restrict__ out, int n4) {
  int i = blockIdx.x * 256 + threadIdx.x;
  int stride = gridDim.x * 256;
  for (; i < n4; i += stride) {
    float4 v = ((const float4*)in)[i];
    ushort4 o;
    o.x = f2bf(v.x); o.y = f2bf(v.y); o.z = f2bf(v.z); o.w = f2bf(v.w);
    ((ushort4*)out)[i] = o;
  }
}

// ---------------------------------------------------------------- layernorm (f32 in, bf16 out)
__device__ __forceinline__ float block_sum256(float v, float* red) {
  #pragma unroll
  for (int o = 32; o > 0; o >>= 1) v += __shfl_xor(v, o);
  int w = threadIdx.x >> 6;
  __syncthreads();
  if ((threadIdx.x & 63) == 0) red[w] = v;
  __syncthreads();
  return red[0] + red[1] + red[2] + red[3];
}

__global__ __launch_bounds__(256) void layernorm_kernel(
    const float* __restrict__ x, const float* __restrict__ sc,
    const float* __restrict__ bi, unsigned short* __restrict__ out) {
  __shared__ float red[4];
  int row = blockIdx.x;
  float4 v = ((const float4*)(x + (size_t)row * D_))[threadIdx.x];
  float sum = block_sum256(v.x + v.y + v.z + v.w, red);
  float mu = sum * (1.0f / D_);
  float dx = v.x - mu, dy = v.y - mu, dz = v.z - mu, dw = v.w - mu;
  float sq = block_sum256(dx*dx + dy*dy + dz*dz + dw*dw, red);
  float r = rsqrtf(sq * (1.0f / D_) + EPS_);
  int c = threadIdx.x * 4;
  float4 s4 = *(const float4*)(sc + c);
  float4 b4 = *(const float4*)(bi + c);
  ushort4 o;
  o.x = f2bf(dx * r * s4.x + b4.x);
  o.y = f2bf(dy * r * s4.y + b4.y);
  o.z = f2bf(dz * r * s4.z + b4.z);
  o.w = f2bf(dw * r * s4.w + b4.w);
  ((ushort4*)(out + (size_t)row * D_))[threadIdx.x] = o;
}

// ---------------------------------------------------------------- MFMA GEMM
// C[M,N] = A[M,K](bf16) * W[N,K](bf16)^T  (+bias) (+relu) (+res f32), fp32 accum.
// 128x128 tile, BK=64, 256 thr = 4 waves (2x2), each wave 64x64 = 4x4 frags of 16x16.
// m97 structure: global_load_lds width=16, 2 barriers/K-step, + bijective XCD swizzle.
#define BM 128
#define BN 128
#define BKg 64

template<bool BIAS, bool RELU, bool RES, bool OUTBF16>
__global__ __launch_bounds__(256) void gemm_mfma(
    const unsigned short* __restrict__ A, const unsigned short* __restrict__ W,
    const float* __restrict__ bias, const float* __restrict__ res,
    void* __restrict__ Cout, int M, int N, int K, int ldc, int nbx) {
  __shared__ unsigned short As[BM * BKg];
  __shared__ unsigned short Bs[BN * BKg];

  // bijective XCD-aware swizzle (m204)
  int nwg = gridDim.x;
  int bid = blockIdx.x;
  int q = nwg >> 3, r = nwg & 7;
  int xcd = bid & 7, sub = bid >> 3;
  int swz = (xcd < r ? xcd * (q + 1) : r * (q + 1) + (xcd - r) * q) + sub;
  int by = swz / nbx, bx = swz % nbx;
  int bm = by * BM, bn = bx * BN;

  const int tid = threadIdx.x;
  const int l = tid & 63, w = tid >> 6;
  const int wm = (w >> 1) * 64, wn = (w & 1) * 64;
  const int lr = l >> 3;            // row within 8-row chunk
  const int lc = (l & 7) << 3;      // col (8 bf16 = 16B)

  const unsigned short* asrc[4];
  const unsigned short* bsrc[4];
  unsigned short* adst[4];
  unsigned short* bdst[4];
  #pragma unroll
  for (int i = 0; i < 4; ++i) {
    int rowa = i * 32 + w * 8;                       // wave-uniform chunk base
    asrc[i] = A + (size_t)(bm + rowa + lr) * K + lc;
    adst[i] = As + rowa * BKg;
    int gn = bn + rowa + lr; if (gn >= N) gn = N - 1;
    bsrc[i] = W + (size_t)gn * K + lc;
    bdst[i] = Bs + rowa * BKg;
  }

  f32x4 acc[4][4] = {};
  for (int k0 = 0; k0 < K; k0 += BKg) {
    __syncthreads();
    #pragma unroll
    for (int i = 0; i < 4; ++i) {
      gll16(asrc[i] + k0, adst[i]);
      gll16(bsrc[i] + k0, bdst[i]);
    }
    __syncthreads();
    short8 af[2][4], bfr[2][4];
    #pragma unroll
    for (int ks = 0; ks < 2; ++ks)
      #pragma unroll
      for (int i = 0; i < 4; ++i) {
        af[ks][i]  = *(const short8*)(As + (wm + i * 16 + (l & 15)) * BKg + ks * 32 + (l >> 4) * 8);
        bfr[ks][i] = *(const short8*)(Bs + (wn + i * 16 + (l & 15)) * BKg + ks * 32 + (l >> 4) * 8);
      }
    #pragma unroll
    for (int ks = 0; ks < 2; ++ks)
      #pragma unroll
      for (int i = 0; i < 4; ++i)
        #pragma unroll
        for (int j = 0; j < 4; ++j)
          acc[i][j] = __builtin_amdgcn_mfma_f32_16x16x32_bf16(af[ks][i], bfr[ks][j], acc[i][j], 0, 0, 0);
  }

  const int er = (l >> 4) * 4;
  const int ec = l & 15;
  #pragma unroll
  for (int j = 0; j < 4; ++j) {
    int col = bn + wn + j * 16 + ec;
    if (col < N) {
      float bv = BIAS ? bias[col] : 0.f;
      #pragma unroll
      for (int i = 0; i < 4; ++i) {
        #pragma unroll
        for (int rr = 0; rr < 4; ++rr) {
          int row = bm + wm + i * 16 + er + rr;
          float v = acc[i][j][rr] + bv;
          if (RELU) v = fmaxf(v, 0.f);
          if (RES)  v += res[(size_t)row * ldc + col];
          if (OUTBF16) ((unsigned short*)Cout)[(size_t)row * ldc + col] = f2bf(v);
          else         ((float*)Cout)[(size_t)row * ldc + col] = v;
        }
      }
    }
  }
}

// ---------------------------------------------------------------- attention (bf16 in/out)
// One wave per (b, h, q-row). Online softmax, per-lane key-strided, LDS merge.
// qkv layout: [M, 3D] bf16, head h at col h*192: q=+0, k=+64, v=+128.
__global__ __launch_bounds__(64) void attn_kernel(
    const unsigned short* __restrict__ qkv, unsigned short* __restrict__ out) {
  const int q = blockIdx.x, h = blockIdx.y, b = blockIdx.z;
  const int lane = threadIdx.x;
  __shared__ float qs[HD_];
  __shared__ float accs[64][HD_ + 1];
  const size_t base = (size_t)(b * S_) * (3 * D_) + h * (3 * HD_);
  qs[lane] = b2f(qkv[base + (size_t)q * (3 * D_) + lane]) * 0.125f;
  __syncthreads();
  float m = -INFINITY, ssum = 0.f;
  float acc[HD_];
  #pragma unroll
  for (int d = 0; d < HD_; ++d) acc[d] = 0.f;

  for (int k = lane; k <= q; k += 64) {
    const unsigned short* kp = qkv + base + (size_t)k * (3 * D_) + HD_;
    float s = 0.f;
    #pragma unroll
    for (int d = 0; d < HD_; d += 8) {
      short8 kv = *(const short8*)(kp + d);
      #pragma unroll
      for (int j = 0; j < 8; ++j)
        s += qs[d + j] * b2f((unsigned short)kv[j]);
    }
    float nm = fmaxf(m, s);
    float corr = __expf(m - nm);
    float p = __expf(s - nm);
    m = nm;
    ssum = ssum * corr + p;
    const unsigned short* vp = kp + HD_;
    #pragma unroll
    for (int d = 0; d < HD_; d += 8) {
      short8 vv = *(const short8*)(vp + d);
      #pragma unroll
      for (int j = 0; j < 8; ++j)
        acc[d + j] = acc[d + j] * corr + p * b2f((unsigned short)vv[j]);
    }
  }
  float gm = m;
  #pragma unroll
  for (int o = 32; o > 0; o >>= 1) gm = fmaxf(gm, __shfl_xor(gm, o));
  float corr = __expf(m - gm);
  float ss = ssum * corr;
  #pragma unroll
  for (int o = 32; o > 0; o >>= 1) ss += __shfl_xor(ss, o);
  #pragma unroll
  for (int d = 0; d < HD_; ++d) accs[lane][d] = acc[d] * corr;
  __syncthreads();
  float o = 0.f;
  #pragma unroll
  for (int ll = 0; ll < 64; ++ll) o += accs[ll][lane];
  out[(size_t)(b * S_ + q) * D_ + h * HD_ + lane] = f2bf(o / ss);
}

// ---------------------------------------------------------------- launch
static inline void cvt(const float* src, unsigned short* dst, size_t n, hipStream_t s) {
  int n4 = (int)(n / 4);
  int blocks = (n4 + 255) / 256;
  if (blocks > 2048) blocks = 2048;
  cvt_bf16_kernel<<<blocks, 256, 0, s>>>(src, dst, n4);
}

extern "C" void kernel_launch(void* const* d_in, const int* in_sizes, int n_in,
                              void* d_out, int out_size, void* d_ws, size_t ws_size,
                              hipStream_t stream) {
  const int*   idx    = (const int*)d_in[0];
  const float* tok    = (const float*)d_in[1];
  const float* pos    = (const float*)d_in[2];
  const float* qkv_w  = (const float*)d_in[3];
  const float* proj_w = (const float*)d_in[4];
  const float* proj_b = (const float*)d_in[5];
  const float* ln1_s  = (const float*)d_in[6];
  const float* ln1_b  = (const float*)d_in[7];
  const float* fc1_w  = (const float*)d_in[8];
  const float* fc1_b  = (const float*)d_in[9];
  const float* fc2_w  = (const float*)d_in[10];
  const float* fc2_b  = (const float*)d_in[11];
  const float* ln2_s  = (const float*)d_in[12];
  const float* ln2_b  = (const float*)d_in[13];
  const float* lnf_s  = (const float*)d_in[14];
  const float* lnf_b  = (const float*)d_in[15];
  const float* head_w = (const float*)d_in[16];
  const float* head_b = (const float*)d_in[17];
  float* out = (float*)d_out;

  // ws layout: x(f32 8MB) | h(4MB) | qkv(12MB) | attn(4MB) | ff(16MB) | wslot(17MB) = 61MB
  float* x = (float*)d_ws;
  unsigned short* h     = (unsigned short*)(x + (size_t)M_ * D_);
  unsigned short* qkv   = h + (size_t)M_ * D_;
  unsigned short* attnb = qkv + (size_t)M_ * 3 * D_;
  unsigned short* ff    = attnb + (size_t)M_ * D_;
  unsigned short* wslot = ff + (size_t)M_ * FF_;

  embed_kernel<<<M_ * D_ / 4 / 256, 256, 0, stream>>>(idx, tok, pos, x);

  for (int l = 0; l < L_; ++l) {
    layernorm_kernel<<<M_, 256, 0, stream>>>(x, ln1_s + l * D_, ln1_b + l * D_, h);
    cvt(qkv_w + (size_t)l * 3 * D_ * D_, wslot, (size_t)3 * D_ * D_, stream);
    {
      int nbx = 3 * D_ / BN, nby = M_ / BM;
      gemm_mfma<false, false, false, true><<<nbx * nby, 256, 0, stream>>>(
          h, wslot, nullptr, nullptr, qkv, M_, 3 * D_, D_, 3 * D_, nbx);
    }
    attn_kernel<<<dim3(S_, H_, B_), 64, 0, stream>>>(qkv, attnb);
    cvt(proj_w + (size_t)l * D_ * D_, wslot, (size_t)D_ * D_, stream);
    {
      int nbx = D_ / BN, nby = M_ / BM;
      gemm_mfma<true, false, true, false><<<nbx * nby, 256, 0, stream>>>(
          attnb, wslot, proj_b + l * D_, x, x, M_, D_, D_, D_, nbx);
    }
    layernorm_kernel<<<M_, 256, 0, stream>>>(x, ln2_s + l * D_, ln2_b + l * D_, h);
    cvt(fc1_w + (size_t)l * FF_ * D_, wslot, (size_t)FF_ * D_, stream);
    {
      int nbx = FF_ / BN, nby = M_ / BM;
      gemm_mfma<true, true, false, true><<<nbx * nby, 256, 0, stream>>>(
          h, wslot, fc1_b + l * FF_, nullptr, ff, M_, FF_, D_, FF_, nbx);
    }
    cvt(fc2_w + (size_t)l * D_ * FF_, wslot, (size_t)D_ * FF_, stream);
    {
      int nbx = D_ / BN, nby = M_ / BM;
      gemm_mfma<true, false, true, false><<<nbx * nby, 256, 0, stream>>>(
          ff, wslot, fc2_b + l * D_, x, x, M_, D_, FF_, D_, nbx);
    }
  }
  layernorm_kernel<<<M_, 256, 0, stream>>>(x, lnf_s, lnf_b, h);

  // head GEMM in 8192-row chunks of W (wslot caps at 16.8MB)
  for (int c0 = 0; c0 < V_; c0 += 8192) {
    int nc = V_ - c0 < 8192 ? V_ - c0 : 8192;
    cvt(head_w + (size_t)c0 * D_, wslot, (size_t)nc * D_, stream);
    int nbx = (nc + BN - 1) / BN, nby = M_ / BM;
    gemm_mfma<true, false, false, false><<<nbx * nby, 256, 0, stream>>>(
        h, wslot, head_b + c0, nullptr, out + c0, M_, nc, D_, V_, nbx);
  }
}

// Round 3
// 2460.867 us; speedup vs baseline: 6.8376x; 3.8315x over previous
//
#include <hip/hip_runtime.h>
#include <hip/hip_bf16.h>
#include <math.h>

#define B_  2
#define S_  1024
#define D_  1024
#define H_  16
#define HD_ 64
#define L_  8
#define FF_ 4096
#define V_  50257
#define M_  (B_ * S_)     // 2048 token rows
#define EPS_ 1e-5f

typedef __attribute__((ext_vector_type(8))) short short8;   // 8 bf16 (4 VGPRs)
typedef __attribute__((ext_vector_type(4))) float f32x4;    // MFMA accum

__device__ __forceinline__ unsigned short f2bf(float f) {
  union { float f; uint32_t u; } c; c.f = f;
  uint32_t r = (c.u + 0x7FFFu + ((c.u >> 16) & 1u)) >> 16;  // RNE
  return (unsigned short)r;
}
__device__ __forceinline__ float b2f(unsigned short u) {
  union { uint32_t u; float f; } c; c.u = ((uint32_t)u) << 16;
  return c.f;
}
__device__ __forceinline__ void gll16(const unsigned short* g, unsigned short* lds) {
  __builtin_amdgcn_global_load_lds(
      (const __attribute__((address_space(1))) void*)g,
      (__attribute__((address_space(3))) void*)lds, 16, 0, 0);
}

// ---------------------------------------------------------------- embed (fp32 x)
__global__ __launch_bounds__(256) void embed_kernel(
    const int* __restrict__ idx, const float* __restrict__ tok,
    const float* __restrict__ pos, float* __restrict__ x) {
  int i = blockIdx.x * 256 + threadIdx.x;
  int m = i >> 8;
  int d4 = i & 255;
  int s = m & (S_ - 1);
  int t = idx[m];
  float4 tv = ((const float4*)(tok + (size_t)t * D_))[d4];
  float4 pv = ((const float4*)(pos + (size_t)s * D_))[d4];
  float4 o;
  o.x = tv.x + pv.x; o.y = tv.y + pv.y; o.z = tv.z + pv.z; o.w = tv.w + pv.w;
  ((float4*)(x + (size_t)m * D_))[d4] = o;
}

// ---------------------------------------------------------------- f32 -> bf16
__global__ __launch_bounds__(256) void cvt_bf16_kernel(
    const float* __restrict__ in, unsigned short* __restrict__ out, int n4) {
  int i = blockIdx.x * 256 + threadIdx.x;
  int stride = gridDim.x * 256;
  for (; i < n4; i += stride) {
    float4 v = ((const float4*)in)[i];
    ushort4 o;
    o.x = f2bf(v.x); o.y = f2bf(v.y); o.z = f2bf(v.z); o.w = f2bf(v.w);
    ((ushort4*)out)[i] = o;
  }
}

// ---------------------------------------------------------------- layernorm (f32 in, bf16 out)
__device__ __forceinline__ float block_sum256(float v, float* red) {
  #pragma unroll
  for (int o = 32; o > 0; o >>= 1) v += __shfl_xor(v, o);
  int w = threadIdx.x >> 6;
  __syncthreads();
  if ((threadIdx.x & 63) == 0) red[w] = v;
  __syncthreads();
  return red[0] + red[1] + red[2] + red[3];
}

__global__ __launch_bounds__(256) void layernorm_kernel(
    const float* __restrict__ x, const float* __restrict__ sc,
    const float* __restrict__ bi, unsigned short* __restrict__ out) {
  __shared__ float red[4];
  int row = blockIdx.x;
  float4 v = ((const float4*)(x + (size_t)row * D_))[threadIdx.x];
  float sum = block_sum256(v.x + v.y + v.z + v.w, red);
  float mu = sum * (1.0f / D_);
  float dx = v.x - mu, dy = v.y - mu, dz = v.z - mu, dw = v.w - mu;
  float sq = block_sum256(dx*dx + dy*dy + dz*dz + dw*dw, red);
  float r = rsqrtf(sq * (1.0f / D_) + EPS_);
  int c = threadIdx.x * 4;
  float4 s4 = *(const float4*)(sc + c);
  float4 b4 = *(const float4*)(bi + c);
  ushort4 o;
  o.x = f2bf(dx * r * s4.x + b4.x);
  o.y = f2bf(dy * r * s4.y + b4.y);
  o.z = f2bf(dz * r * s4.z + b4.z);
  o.w = f2bf(dw * r * s4.w + b4.w);
  ((ushort4*)(out + (size_t)row * D_))[threadIdx.x] = o;
}

// ---------------------------------------------------------------- MFMA GEMM
// C[M,N] = A[M,K](bf16) * W[N,K](bf16)^T  (+bias) (+relu) (+res f32), fp32 accum.
// 128x128 tile, BK=64, 256 thr = 4 waves (2x2), each wave 64x64 = 4x4 frags of 16x16.
#define BM 128
#define BN 128
#define BKg 64

template<bool BIAS, bool RELU, bool RES, bool OUTBF16>
__global__ __launch_bounds__(256) void gemm_mfma(
    const unsigned short* __restrict__ A, const unsigned short* __restrict__ W,
    const float* __restrict__ bias, const float* __restrict__ res,
    void* __restrict__ Cout, int M, int N, int K, int ldc, int nbx) {
  __shared__ unsigned short As[BM * BKg];
  __shared__ unsigned short Bs[BN * BKg];

  // bijective XCD-aware swizzle (m204)
  int nwg = gridDim.x;
  int bid = blockIdx.x;
  int q = nwg >> 3, r = nwg & 7;
  int xcd = bid & 7, sub = bid >> 3;
  int swz = (xcd < r ? xcd * (q + 1) : r * (q + 1) + (xcd - r) * q) + sub;
  int by = swz / nbx, bx = swz % nbx;
  int bm = by * BM, bn = bx * BN;

  const int tid = threadIdx.x;
  const int l = tid & 63, w = tid >> 6;
  const int wm = (w >> 1) * 64, wn = (w & 1) * 64;
  const int lr = l >> 3;            // row within 8-row chunk
  const int lc = (l & 7) << 3;      // col (8 bf16 = 16B)

  const unsigned short* asrc[4];
  const unsigned short* bsrc[4];
  unsigned short* adst[4];
  unsigned short* bdst[4];
  #pragma unroll
  for (int i = 0; i < 4; ++i) {
    int rowa = i * 32 + w * 8;                       // wave-uniform chunk base
    asrc[i] = A + (size_t)(bm + rowa + lr) * K + lc;
    adst[i] = As + rowa * BKg;
    int gn = bn + rowa + lr; if (gn >= N) gn = N - 1;
    bsrc[i] = W + (size_t)gn * K + lc;
    bdst[i] = Bs + rowa * BKg;
  }

  f32x4 acc[4][4] = {};
  for (int k0 = 0; k0 < K; k0 += BKg) {
    __syncthreads();
    #pragma unroll
    for (int i = 0; i < 4; ++i) {
      gll16(asrc[i] + k0, adst[i]);
      gll16(bsrc[i] + k0, bdst[i]);
    }
    __syncthreads();
    short8 af[2][4], bfr[2][4];
    #pragma unroll
    for (int ks = 0; ks < 2; ++ks)
      #pragma unroll
      for (int i = 0; i < 4; ++i) {
        af[ks][i]  = *(const short8*)(As + (wm + i * 16 + (l & 15)) * BKg + ks * 32 + (l >> 4) * 8);
        bfr[ks][i] = *(const short8*)(Bs + (wn + i * 16 + (l & 15)) * BKg + ks * 32 + (l >> 4) * 8);
      }
    #pragma unroll
    for (int ks = 0; ks < 2; ++ks)
      #pragma unroll
      for (int i = 0; i < 4; ++i)
        #pragma unroll
        for (int j = 0; j < 4; ++j)
          acc[i][j] = __builtin_amdgcn_mfma_f32_16x16x32_bf16(af[ks][i], bfr[ks][j], acc[i][j], 0, 0, 0);
  }

  const int er = (l >> 4) * 4;
  const int ec = l & 15;
  #pragma unroll
  for (int j = 0; j < 4; ++j) {
    int col = bn + wn + j * 16 + ec;
    if (col < N) {
      float bv = BIAS ? bias[col] : 0.f;
      #pragma unroll
      for (int i = 0; i < 4; ++i) {
        #pragma unroll
        for (int rr = 0; rr < 4; ++rr) {
          int row = bm + wm + i * 16 + er + rr;
          float v = acc[i][j][rr] + bv;
          if (RELU) v = fmaxf(v, 0.f);
          if (RES)  v += res[(size_t)row * ldc + col];
          if (OUTBF16) ((unsigned short*)Cout)[(size_t)row * ldc + col] = f2bf(v);
          else         ((float*)Cout)[(size_t)row * ldc + col] = v;
        }
      }
    }
  }
}

// ---------------------------------------------------------------- MFMA flash attention
// Block: 256 thr (4 waves), one (b,h). Two 64-row Q-tiles per block, paired
// (p, 15-p) so every block does exactly 17 KV-tile steps (causal balance).
// Each wave owns 16 q-rows. KV tiles of 64 staged in LDS [64][72] (pad kills
// the stride-128B bank conflict); V stored transposed. Online softmax via
// 16-lane shfl_xor reductions; P re-laid out through per-wave padded LDS.
__global__ __launch_bounds__(256) void attn_mfma_kernel(
    const unsigned short* __restrict__ qkv, unsigned short* __restrict__ out) {
  __shared__ unsigned short Kl[64 * 72];
  __shared__ unsigned short Vt[64 * 72];          // Vt[d][k]
  __shared__ unsigned short Pl[4 * 16 * 72];      // per-wave P[16][72]
  const int pair = blockIdx.x, h = blockIdx.y, b = blockIdx.z;
  const int tid = threadIdx.x;
  const int l = tid & 63, wid = tid >> 6;
  const int g = l >> 4, m15 = l & 15;
  const size_t rs = 3 * D_;                        // qkv row stride
  const unsigned short* base = qkv + (size_t)(b * S_) * rs + h * (3 * HD_);
  const int sk = tid & 63;                         // staged k-row
  const int sd = wid * 16;                         // staged d0
  unsigned short* Pw = Pl + wid * 16 * 72;

  for (int pass = 0; pass < 2; ++pass) {
    const int q0 = (pass ? (15 - pair) : pair) * 64;
    const int nt = q0 / 64 + 1;
    // Q fragments (A-operand): row m15, k = g*8 + ks*32
    const unsigned short* qp = base + (size_t)(q0 + wid * 16 + m15) * rs + g * 8;
    short8 qf0 = *(const short8*)(qp);
    short8 qf1 = *(const short8*)(qp + 32);
    f32x4 acc_o[4] = {};
    float mrun[4] = {-INFINITY, -INFINITY, -INFINITY, -INFINITY};
    float ssum[4] = {0.f, 0.f, 0.f, 0.f};

    for (int kt = 0; kt < nt; ++kt) {
      const int k64 = kt * 64;
      __syncthreads();                             // prior reads done
      // stage K [64][72] and Vt [64][72] (reg -> LDS, V transposed)
      const unsigned short* krp = base + (size_t)(k64 + sk) * rs + HD_ + sd;
      short8 kv0 = *(const short8*)(krp);
      short8 kv1 = *(const short8*)(krp + 8);
      const unsigned short* vrp = krp + HD_;
      short8 vv0 = *(const short8*)(vrp);
      short8 vv1 = *(const short8*)(vrp + 8);
      *(short8*)(Kl + sk * 72 + sd) = kv0;
      *(short8*)(Kl + sk * 72 + sd + 8) = kv1;
      #pragma unroll
      for (int e = 0; e < 8; ++e) {
        Vt[(sd + e) * 72 + sk] = (unsigned short)vv0[e];
        Vt[(sd + 8 + e) * 72 + sk] = (unsigned short)vv1[e];
      }
      __syncthreads();

      // QK^T: S[16q x 64k] per wave
      f32x4 sc[4] = {};
      #pragma unroll
      for (int j = 0; j < 4; ++j) {
        short8 kf0 = *(const short8*)(Kl + (j * 16 + m15) * 72 + g * 8);
        short8 kf1 = *(const short8*)(Kl + (j * 16 + m15) * 72 + 32 + g * 8);
        sc[j] = __builtin_amdgcn_mfma_f32_16x16x32_bf16(qf0, kf0, sc[j], 0, 0, 0);
        sc[j] = __builtin_amdgcn_mfma_f32_16x16x32_bf16(qf1, kf1, sc[j], 0, 0, 0);
      }

      const bool lastt = (kt == nt - 1);
      #pragma unroll
      for (int rr = 0; rr < 4; ++rr) {
        const int qrow = q0 + wid * 16 + g * 4 + rr;
        float sv[4];
        #pragma unroll
        for (int j = 0; j < 4; ++j) {
          sv[j] = sc[j][rr] * 0.125f;
          if (lastt && (k64 + j * 16 + m15 > qrow)) sv[j] = -1e30f;
        }
        float mx = fmaxf(fmaxf(sv[0], sv[1]), fmaxf(sv[2], sv[3]));
        mx = fmaxf(mx, __shfl_xor(mx, 1));
        mx = fmaxf(mx, __shfl_xor(mx, 2));
        mx = fmaxf(mx, __shfl_xor(mx, 4));
        mx = fmaxf(mx, __shfl_xor(mx, 8));
        float mn = fmaxf(mrun[rr], mx);
        float corr = __expf(mrun[rr] - mn);        // -inf start -> 0, mn finite
        mrun[rr] = mn;
        float ts = 0.f;
        #pragma unroll
        for (int j = 0; j < 4; ++j) {
          float p = __expf(sv[j] - mn);
          ts += p;
          Pw[(g * 4 + rr) * 72 + j * 16 + m15] = f2bf(p);
        }
        ts += __shfl_xor(ts, 1); ts += __shfl_xor(ts, 2);
        ts += __shfl_xor(ts, 4); ts += __shfl_xor(ts, 8);
        ssum[rr] = ssum[rr] * corr + ts;
        #pragma unroll
        for (int j = 0; j < 4; ++j) acc_o[j][rr] *= corr;
      }

      // PV: O[16q x 64d] += P[16q x 64k] * V[64k x 64d]
      short8 pa0 = *(const short8*)(Pw + m15 * 72 + g * 8);
      short8 pa1 = *(const short8*)(Pw + m15 * 72 + 32 + g * 8);
      #pragma unroll
      for (int j = 0; j < 4; ++j) {
        short8 vb0 = *(const short8*)(Vt + (j * 16 + m15) * 72 + g * 8);
        short8 vb1 = *(const short8*)(Vt + (j * 16 + m15) * 72 + 32 + g * 8);
        acc_o[j] = __builtin_amdgcn_mfma_f32_16x16x32_bf16(pa0, vb0, acc_o[j], 0, 0, 0);
        acc_o[j] = __builtin_amdgcn_mfma_f32_16x16x32_bf16(pa1, vb1, acc_o[j], 0, 0, 0);
      }
    }

    #pragma unroll
    for (int rr = 0; rr < 4; ++rr) {
      const int qrow = q0 + wid * 16 + g * 4 + rr;
      float inv = 1.0f / ssum[rr];
      #pragma unroll
      for (int j = 0; j < 4; ++j)
        out[(size_t)(b * S_ + qrow) * D_ + h * HD_ + j * 16 + m15] =
            f2bf(acc_o[j][rr] * inv);
    }
  }
}

// ---------------------------------------------------------------- launch
static inline void cvt(const float* src, unsigned short* dst, size_t n, hipStream_t s) {
  int n4 = (int)(n / 4);
  int blocks = (n4 + 255) / 256;
  if (blocks > 2048) blocks = 2048;
  cvt_bf16_kernel<<<blocks, 256, 0, s>>>(src, dst, n4);
}

extern "C" void kernel_launch(void* const* d_in, const int* in_sizes, int n_in,
                              void* d_out, int out_size, void* d_ws, size_t ws_size,
                              hipStream_t stream) {
  const int*   idx    = (const int*)d_in[0];
  const float* tok    = (const float*)d_in[1];
  const float* pos    = (const float*)d_in[2];
  const float* qkv_w  = (const float*)d_in[3];
  const float* proj_w = (const float*)d_in[4];
  const float* proj_b = (const float*)d_in[5];
  const float* ln1_s  = (const float*)d_in[6];
  const float* ln1_b  = (const float*)d_in[7];
  const float* fc1_w  = (const float*)d_in[8];
  const float* fc1_b  = (const float*)d_in[9];
  const float* fc2_w  = (const float*)d_in[10];
  const float* fc2_b  = (const float*)d_in[11];
  const float* ln2_s  = (const float*)d_in[12];
  const float* ln2_b  = (const float*)d_in[13];
  const float* lnf_s  = (const float*)d_in[14];
  const float* lnf_b  = (const float*)d_in[15];
  const float* head_w = (const float*)d_in[16];
  const float* head_b = (const float*)d_in[17];
  float* out = (float*)d_out;

  // ws layout: x(f32 8MB) | h(4MB) | qkv(12MB) | attn(4MB) | ff(16MB) | wslot(17MB)
  float* x = (float*)d_ws;
  unsigned short* h     = (unsigned short*)(x + (size_t)M_ * D_);
  unsigned short* qkv   = h + (size_t)M_ * D_;
  unsigned short* attnb = qkv + (size_t)M_ * 3 * D_;
  unsigned short* ff    = attnb + (size_t)M_ * D_;
  unsigned short* wslot = ff + (size_t)M_ * FF_;

  embed_kernel<<<M_ * D_ / 4 / 256, 256, 0, stream>>>(idx, tok, pos, x);

  for (int l = 0; l < L_; ++l) {
    layernorm_kernel<<<M_, 256, 0, stream>>>(x, ln1_s + l * D_, ln1_b + l * D_, h);
    cvt(qkv_w + (size_t)l * 3 * D_ * D_, wslot, (size_t)3 * D_ * D_, stream);
    {
      int nbx = 3 * D_ / BN, nby = M_ / BM;
      gemm_mfma<false, false, false, true><<<nbx * nby, 256, 0, stream>>>(
          h, wslot, nullptr, nullptr, qkv, M_, 3 * D_, D_, 3 * D_, nbx);
    }
    attn_mfma_kernel<<<dim3(8, H_, B_), 256, 0, stream>>>(qkv, attnb);
    cvt(proj_w + (size_t)l * D_ * D_, wslot, (size_t)D_ * D_, stream);
    {
      int nbx = D_ / BN, nby = M_ / BM;
      gemm_mfma<true, false, true, false><<<nbx * nby, 256, 0, stream>>>(
          attnb, wslot, proj_b + l * D_, x, x, M_, D_, D_, D_, nbx);
    }
    layernorm_kernel<<<M_, 256, 0, stream>>>(x, ln2_s + l * D_, ln2_b + l * D_, h);
    cvt(fc1_w + (size_t)l * FF_ * D_, wslot, (size_t)FF_ * D_, stream);
    {
      int nbx = FF_ / BN, nby = M_ / BM;
      gemm_mfma<true, true, false, true><<<nbx * nby, 256, 0, stream>>>(
          h, wslot, fc1_b + l * FF_, nullptr, ff, M_, FF_, D_, FF_, nbx);
    }
    cvt(fc2_w + (size_t)l * D_ * FF_, wslot, (size_t)D_ * FF_, stream);
    {
      int nbx = D_ / BN, nby = M_ / BM;
      gemm_mfma<true, false, true, false><<<nbx * nby, 256, 0, stream>>>(
          ff, wslot, fc2_b + l * D_, x, x, M_, D_, FF_, D_, nbx);
    }
  }
  layernorm_kernel<<<M_, 256, 0, stream>>>(x, lnf_s, lnf_b, h);

  // head GEMM in 8192-row chunks of W (wslot caps at 16.8MB)
  for (int c0 = 0; c0 < V_; c0 += 8192) {
    int nc = V_ - c0 < 8192 ? V_ - c0 : 8192;
    cvt(head_w + (size_t)c0 * D_, wslot, (size_t)nc * D_, stream);
    int nbx = (nc + BN - 1) / BN, nby = M_ / BM;
    gemm_mfma<true, false, false, false><<<nbx * nby, 256, 0, stream>>>(
        h, wslot, head_b + c0, nullptr, out + c0, M_, nc, D_, V_, nbx);
  }
}

// Round 4
// 2027.549 us; speedup vs baseline: 8.2988x; 1.2137x over previous
//
#include <hip/hip_runtime.h>
#include <hip/hip_bf16.h>
#include <math.h>

#define B_  2
#define S_  1024
#define D_  1024
#define H_  16
#define HD_ 64
#define L_  8
#define FF_ 4096
#define V_  50257
#define M_  (B_ * S_)     // 2048 token rows
#define EPS_ 1e-5f

typedef __attribute__((ext_vector_type(8))) short short8;   // 8 bf16 (4 VGPRs)
typedef __attribute__((ext_vector_type(4))) float f32x4;    // MFMA accum

__device__ __forceinline__ unsigned short f2bf(float f) {
  union { float f; uint32_t u; } c; c.f = f;
  uint32_t r = (c.u + 0x7FFFu + ((c.u >> 16) & 1u)) >> 16;  // RNE
  return (unsigned short)r;
}
__device__ __forceinline__ float b2f(unsigned short u) {
  union { uint32_t u; float f; } c; c.u = ((uint32_t)u) << 16;
  return c.f;
}
__device__ __forceinline__ void gll16(const unsigned short* g, unsigned short* lds) {
  __builtin_amdgcn_global_load_lds(
      (const __attribute__((address_space(1))) void*)g,
      (__attribute__((address_space(3))) void*)lds, 16, 0, 0);
}

// ---------------------------------------------------------------- embed (fp32 x)
__global__ __launch_bounds__(256) void embed_kernel(
    const int* __restrict__ idx, const float* __restrict__ tok,
    const float* __restrict__ pos, float* __restrict__ x) {
  int i = blockIdx.x * 256 + threadIdx.x;
  int m = i >> 8;
  int d4 = i & 255;
  int s = m & (S_ - 1);
  int t = idx[m];
  float4 tv = ((const float4*)(tok + (size_t)t * D_))[d4];
  float4 pv = ((const float4*)(pos + (size_t)s * D_))[d4];
  float4 o;
  o.x = tv.x + pv.x; o.y = tv.y + pv.y; o.z = tv.z + pv.z; o.w = tv.w + pv.w;
  ((float4*)(x + (size_t)m * D_))[d4] = o;
}

// ---------------------------------------------------------------- f32 -> bf16 (single)
__global__ __launch_bounds__(256) void cvt_bf16_kernel(
    const float* __restrict__ in, unsigned short* __restrict__ out, int n4) {
  int i = blockIdx.x * 256 + threadIdx.x;
  int stride = gridDim.x * 256;
  for (; i < n4; i += stride) {
    float4 v = ((const float4*)in)[i];
    ushort4 o;
    o.x = f2bf(v.x); o.y = f2bf(v.y); o.z = f2bf(v.z); o.w = f2bf(v.w);
    ((ushort4*)out)[i] = o;
  }
}

// ---------------------------------------------------------------- f32 -> bf16 (4 segments)
__global__ __launch_bounds__(256) void cvt4_kernel(
    const float* __restrict__ s0, const float* __restrict__ s1,
    const float* __restrict__ s2, const float* __restrict__ s3,
    unsigned short* __restrict__ d0, unsigned short* __restrict__ d1,
    unsigned short* __restrict__ d2, unsigned short* __restrict__ d3,
    int n0, int n1, int n2, int n3) {          // float4 units
  int total = n0 + n1 + n2 + n3;
  for (int i = blockIdx.x * 256 + threadIdx.x; i < total; i += gridDim.x * 256) {
    const float* s; unsigned short* d; int j = i;
    if (j < n0)              { s = s0; d = d0; }
    else if ((j -= n0) < n1) { s = s1; d = d1; }
    else if ((j -= n1) < n2) { s = s2; d = d2; }
    else                     { j -= n2; s = s3; d = d3; }
    float4 v = ((const float4*)s)[j];
    ushort4 o;
    o.x = f2bf(v.x); o.y = f2bf(v.y); o.z = f2bf(v.z); o.w = f2bf(v.w);
    ((ushort4*)d)[j] = o;
  }
}

// ---------------------------------------------------------------- split-K reduce
// x[i] += bias[col] + p0[i] + p1[i]   (f32, in-place residual)
__global__ __launch_bounds__(256) void reduce2_kernel(
    const float* __restrict__ p0, const float* __restrict__ p1,
    const float* __restrict__ bias, float* __restrict__ x, int total4) {
  int i = blockIdx.x * 256 + threadIdx.x;
  if (i >= total4) return;
  float4 a = ((const float4*)p0)[i];
  float4 b = ((const float4*)p1)[i];
  float4 r = ((const float4*)x)[i];
  float4 bb = ((const float4*)bias)[i & 255];      // N=1024 -> 256 float4/row
  float4 o;
  o.x = r.x + a.x + b.x + bb.x;
  o.y = r.y + a.y + b.y + bb.y;
  o.z = r.z + a.z + b.z + bb.z;
  o.w = r.w + a.w + b.w + bb.w;
  ((float4*)x)[i] = o;
}

// ---------------------------------------------------------------- layernorm (f32 in, bf16 out)
__device__ __forceinline__ float block_sum256(float v, float* red) {
  #pragma unroll
  for (int o = 32; o > 0; o >>= 1) v += __shfl_xor(v, o);
  int w = threadIdx.x >> 6;
  __syncthreads();
  if ((threadIdx.x & 63) == 0) red[w] = v;
  __syncthreads();
  return red[0] + red[1] + red[2] + red[3];
}

__global__ __launch_bounds__(256) void layernorm_kernel(
    const float* __restrict__ x, const float* __restrict__ sc,
    const float* __restrict__ bi, unsigned short* __restrict__ out) {
  __shared__ float red[4];
  int row = blockIdx.x;
  float4 v = ((const float4*)(x + (size_t)row * D_))[threadIdx.x];
  float sum = block_sum256(v.x + v.y + v.z + v.w, red);
  float mu = sum * (1.0f / D_);
  float dx = v.x - mu, dy = v.y - mu, dz = v.z - mu, dw = v.w - mu;
  float sq = block_sum256(dx*dx + dy*dy + dz*dz + dw*dw, red);
  float r = rsqrtf(sq * (1.0f / D_) + EPS_);
  int c = threadIdx.x * 4;
  float4 s4 = *(const float4*)(sc + c);
  float4 b4 = *(const float4*)(bi + c);
  ushort4 o;
  o.x = f2bf(dx * r * s4.x + b4.x);
  o.y = f2bf(dy * r * s4.y + b4.y);
  o.z = f2bf(dz * r * s4.z + b4.z);
  o.w = f2bf(dw * r * s4.w + b4.w);
  ((ushort4*)(out + (size_t)row * D_))[threadIdx.x] = o;
}

// ---------------------------------------------------------------- MFMA GEMM
// C[M,N] = A[M,Koff:Koff+K] * W[N,Koff:Koff+K]^T (+bias)(+relu), fp32 accum.
// Row stride of A/W is lda. blockIdx.y = K-split index; Koff = z*K; output
// pointer advanced by z*zstride elements. 128x128 tile, BK=64, 4 waves.
#define BM 128
#define BN 128
#define BKg 64

template<bool BIAS, bool RELU, bool OUTBF16>
__global__ __launch_bounds__(256) void gemm_mfma(
    const unsigned short* __restrict__ A, const unsigned short* __restrict__ W,
    const float* __restrict__ bias, void* __restrict__ Cout,
    int M, int N, int K, int lda, int ldc, size_t zstride, int nbx) {
  __shared__ unsigned short As[BM * BKg];
  __shared__ unsigned short Bs[BN * BKg];

  // bijective XCD-aware swizzle (m204)
  int nwg = gridDim.x;
  int bid = blockIdx.x;
  int q = nwg >> 3, r = nwg & 7;
  int xcd = bid & 7, sub = bid >> 3;
  int swz = (xcd < r ? xcd * (q + 1) : r * (q + 1) + (xcd - r) * q) + sub;
  int by = swz / nbx, bx = swz % nbx;
  int bm = by * BM, bn = bx * BN;

  const size_t Koff = (size_t)blockIdx.y * K;
  const unsigned short* Ab = A + Koff;
  const unsigned short* Wb = W + Koff;

  const int tid = threadIdx.x;
  const int l = tid & 63, w = tid >> 6;
  const int wm = (w >> 1) * 64, wn = (w & 1) * 64;
  const int lr = l >> 3;            // row within 8-row chunk
  const int lc = (l & 7) << 3;      // col (8 bf16 = 16B)

  const unsigned short* asrc[4];
  const unsigned short* bsrc[4];
  unsigned short* adst[4];
  unsigned short* bdst[4];
  #pragma unroll
  for (int i = 0; i < 4; ++i) {
    int rowa = i * 32 + w * 8;                       // wave-uniform chunk base
    asrc[i] = Ab + (size_t)(bm + rowa + lr) * lda + lc;
    adst[i] = As + rowa * BKg;
    int gn = bn + rowa + lr; if (gn >= N) gn = N - 1;
    bsrc[i] = Wb + (size_t)gn * lda + lc;
    bdst[i] = Bs + rowa * BKg;
  }

  f32x4 acc[4][4] = {};
  for (int k0 = 0; k0 < K; k0 += BKg) {
    __syncthreads();
    #pragma unroll
    for (int i = 0; i < 4; ++i) {
      gll16(asrc[i] + k0, adst[i]);
      gll16(bsrc[i] + k0, bdst[i]);
    }
    __syncthreads();
    short8 af[2][4], bfr[2][4];
    #pragma unroll
    for (int ks = 0; ks < 2; ++ks)
      #pragma unroll
      for (int i = 0; i < 4; ++i) {
        af[ks][i]  = *(const short8*)(As + (wm + i * 16 + (l & 15)) * BKg + ks * 32 + (l >> 4) * 8);
        bfr[ks][i] = *(const short8*)(Bs + (wn + i * 16 + (l & 15)) * BKg + ks * 32 + (l >> 4) * 8);
      }
    #pragma unroll
    for (int ks = 0; ks < 2; ++ks)
      #pragma unroll
      for (int i = 0; i < 4; ++i)
        #pragma unroll
        for (int j = 0; j < 4; ++j)
          acc[i][j] = __builtin_amdgcn_mfma_f32_16x16x32_bf16(af[ks][i], bfr[ks][j], acc[i][j], 0, 0, 0);
  }

  const size_t zoff = (size_t)blockIdx.y * zstride;
  const int er = (l >> 4) * 4;
  const int ec = l & 15;
  #pragma unroll
  for (int j = 0; j < 4; ++j) {
    int col = bn + wn + j * 16 + ec;
    if (col < N) {
      float bv = BIAS ? bias[col] : 0.f;
      #pragma unroll
      for (int i = 0; i < 4; ++i) {
        #pragma unroll
        for (int rr = 0; rr < 4; ++rr) {
          int row = bm + wm + i * 16 + er + rr;
          float v = acc[i][j][rr] + bv;
          if (RELU) v = fmaxf(v, 0.f);
          if (OUTBF16) ((unsigned short*)Cout + zoff)[(size_t)row * ldc + col] = f2bf(v);
          else         ((float*)Cout + zoff)[(size_t)row * ldc + col] = v;
        }
      }
    }
  }
}

// ---------------------------------------------------------------- MFMA flash attention
// Grid (16, H, B): 512 blocks, 2/CU. tile = b ? x : 15-x so the two co-resident
// blocks per CU sum to 17 KV-steps (long+short), longest dispatched first.
// T14 async-STAGE: next KV tile global-loaded into regs under current compute.
__global__ __launch_bounds__(256) void attn_mfma_kernel(
    const unsigned short* __restrict__ qkv, unsigned short* __restrict__ out) {
  __shared__ unsigned short Kl[64 * 72];
  __shared__ unsigned short Vt[64 * 72];          // Vt[d][k]
  __shared__ unsigned short Pl[4 * 16 * 72];      // per-wave P[16][72]
  const int h = blockIdx.y, b = blockIdx.z;
  const int tile = b ? blockIdx.x : (15 - blockIdx.x);
  const int q0 = tile * 64;
  const int nt = tile + 1;
  const int tid = threadIdx.x;
  const int l = tid & 63, wid = tid >> 6;
  const int g = l >> 4, m15 = l & 15;
  const size_t rs = 3 * D_;                        // qkv row stride
  const unsigned short* base = qkv + (size_t)(b * S_) * rs + h * (3 * HD_);
  const int sk = l;                                // staged k-row
  const int sd = wid * 16;                         // staged d0
  unsigned short* Pw = Pl + wid * 16 * 72;

  // Q fragments (A-operand): row m15, k = g*8 + ks*32
  const unsigned short* qp = base + (size_t)(q0 + wid * 16 + m15) * rs + g * 8;
  short8 qf0 = *(const short8*)(qp);
  short8 qf1 = *(const short8*)(qp + 32);
  f32x4 acc_o[4] = {};
  float mrun[4] = {-INFINITY, -INFINITY, -INFINITY, -INFINITY};
  float ssum[4] = {0.f, 0.f, 0.f, 0.f};

  // prefetch KV tile 0 into regs
  const unsigned short* krp = base + (size_t)sk * rs + HD_ + sd;
  short8 kv0 = *(const short8*)(krp);
  short8 kv1 = *(const short8*)(krp + 8);
  short8 vv0 = *(const short8*)(krp + HD_);
  short8 vv1 = *(const short8*)(krp + HD_ + 8);

  for (int kt = 0; kt < nt; ++kt) {
    const int k64 = kt * 64;
    __syncthreads();                               // prior LDS reads done
    *(short8*)(Kl + sk * 72 + sd) = kv0;
    *(short8*)(Kl + sk * 72 + sd + 8) = kv1;
    #pragma unroll
    for (int e = 0; e < 8; ++e) {
      Vt[(sd + e) * 72 + sk] = (unsigned short)vv0[e];
      Vt[(sd + 8 + e) * 72 + sk] = (unsigned short)vv1[e];
    }
    __syncthreads();
    if (kt + 1 < nt) {                             // T14: issue next-tile loads now
      const unsigned short* krn = base + (size_t)(k64 + 64 + sk) * rs + HD_ + sd;
      kv0 = *(const short8*)(krn);
      kv1 = *(const short8*)(krn + 8);
      vv0 = *(const short8*)(krn + HD_);
      vv1 = *(const short8*)(krn + HD_ + 8);
    }

    // QK^T: S[16q x 64k] per wave
    f32x4 sc[4] = {};
    #pragma unroll
    for (int j = 0; j < 4; ++j) {
      short8 kf0 = *(const short8*)(Kl + (j * 16 + m15) * 72 + g * 8);
      short8 kf1 = *(const short8*)(Kl + (j * 16 + m15) * 72 + 32 + g * 8);
      sc[j] = __builtin_amdgcn_mfma_f32_16x16x32_bf16(qf0, kf0, sc[j], 0, 0, 0);
      sc[j] = __builtin_amdgcn_mfma_f32_16x16x32_bf16(qf1, kf1, sc[j], 0, 0, 0);
    }

    const bool lastt = (kt == nt - 1);
    #pragma unroll
    for (int rr = 0; rr < 4; ++rr) {
      const int qrow = q0 + wid * 16 + g * 4 + rr;
      float sv[4];
      #pragma unroll
      for (int j = 0; j < 4; ++j) {
        sv[j] = sc[j][rr] * 0.125f;
        if (lastt && (k64 + j * 16 + m15 > qrow)) sv[j] = -1e30f;
      }
      float mx = fmaxf(fmaxf(sv[0], sv[1]), fmaxf(sv[2], sv[3]));
      mx = fmaxf(mx, __shfl_xor(mx, 1));
      mx = fmaxf(mx, __shfl_xor(mx, 2));
      mx = fmaxf(mx, __shfl_xor(mx, 4));
      mx = fmaxf(mx, __shfl_xor(mx, 8));
      float mn = fmaxf(mrun[rr], mx);
      float corr = __expf(mrun[rr] - mn);
      mrun[rr] = mn;
      float ts = 0.f;
      #pragma unroll
      for (int j = 0; j < 4; ++j) {
        float p = __expf(sv[j] - mn);
        ts += p;
        Pw[(g * 4 + rr) * 72 + j * 16 + m15] = f2bf(p);
      }
      ts += __shfl_xor(ts, 1); ts += __shfl_xor(ts, 2);
      ts += __shfl_xor(ts, 4); ts += __shfl_xor(ts, 8);
      ssum[rr] = ssum[rr] * corr + ts;
      #pragma unroll
      for (int j = 0; j < 4; ++j) acc_o[j][rr] *= corr;
    }

    // PV: O[16q x 64d] += P[16q x 64k] * V[64k x 64d]
    short8 pa0 = *(const short8*)(Pw + m15 * 72 + g * 8);
    short8 pa1 = *(const short8*)(Pw + m15 * 72 + 32 + g * 8);
    #pragma unroll
    for (int j = 0; j < 4; ++j) {
      short8 vb0 = *(const short8*)(Vt + (j * 16 + m15) * 72 + g * 8);
      short8 vb1 = *(const short8*)(Vt + (j * 16 + m15) * 72 + 32 + g * 8);
      acc_o[j] = __builtin_amdgcn_mfma_f32_16x16x32_bf16(pa0, vb0, acc_o[j], 0, 0, 0);
      acc_o[j] = __builtin_amdgcn_mfma_f32_16x16x32_bf16(pa1, vb1, acc_o[j], 0, 0, 0);
    }
  }

  #pragma unroll
  for (int rr = 0; rr < 4; ++rr) {
    const int qrow = q0 + wid * 16 + g * 4 + rr;
    float inv = 1.0f / ssum[rr];
    #pragma unroll
    for (int j = 0; j < 4; ++j)
      out[(size_t)(b * S_ + qrow) * D_ + h * HD_ + j * 16 + m15] =
          f2bf(acc_o[j][rr] * inv);
  }
}

// ---------------------------------------------------------------- launch
static inline void cvt(const float* src, unsigned short* dst, size_t n, hipStream_t s) {
  int n4 = (int)(n / 4);
  int blocks = (n4 + 255) / 256;
  if (blocks > 2048) blocks = 2048;
  cvt_bf16_kernel<<<blocks, 256, 0, s>>>(src, dst, n4);
}

extern "C" void kernel_launch(void* const* d_in, const int* in_sizes, int n_in,
                              void* d_out, int out_size, void* d_ws, size_t ws_size,
                              hipStream_t stream) {
  const int*   idx    = (const int*)d_in[0];
  const float* tok    = (const float*)d_in[1];
  const float* pos    = (const float*)d_in[2];
  const float* qkv_w  = (const float*)d_in[3];
  const float* proj_w = (const float*)d_in[4];
  const float* proj_b = (const float*)d_in[5];
  const float* ln1_s  = (const float*)d_in[6];
  const float* ln1_b  = (const float*)d_in[7];
  const float* fc1_w  = (const float*)d_in[8];
  const float* fc1_b  = (const float*)d_in[9];
  const float* fc2_w  = (const float*)d_in[10];
  const float* fc2_b  = (const float*)d_in[11];
  const float* ln2_s  = (const float*)d_in[12];
  const float* ln2_b  = (const float*)d_in[13];
  const float* lnf_s  = (const float*)d_in[14];
  const float* lnf_b  = (const float*)d_in[15];
  const float* head_w = (const float*)d_in[16];
  const float* head_b = (const float*)d_in[17];
  float* out = (float*)d_out;

  // ws layout (MiB offsets): x@0(8,f32) h@8(4) qkvb@12(12) attnb@24(4) ff@28(16)
  //   wq@44(6) wp@50(2) w1@52(8) w2@60(8)  -> total 68 MiB (<= 80 proven).
  // split-K partials (2 x 8MiB f32) overlay h+qkvb @8..24 (dead during proj/fc2).
  // head chunks (16 MiB) overlay wq..w1 @44..60.
  char* wsb = (char*)d_ws;
  float*          x      = (float*)(wsb);
  unsigned short* h      = (unsigned short*)(wsb + (8u << 20));
  unsigned short* qkvb   = (unsigned short*)(wsb + (12u << 20));
  unsigned short* attnb  = (unsigned short*)(wsb + (24u << 20));
  unsigned short* ff     = (unsigned short*)(wsb + (28u << 20));
  unsigned short* wq     = (unsigned short*)(wsb + (44u << 20));
  unsigned short* wp     = (unsigned short*)(wsb + (50u << 20));
  unsigned short* w1     = (unsigned short*)(wsb + (52u << 20));
  unsigned short* w2     = (unsigned short*)(wsb + (60u << 20));
  float*          part0  = (float*)(wsb + (8u << 20));
  float*          part1  = (float*)(wsb + (16u << 20));

  embed_kernel<<<M_ * D_ / 4 / 256, 256, 0, stream>>>(idx, tok, pos, x);

  const int total4 = M_ * D_ / 4;                  // 524288 -> 2048 blocks
  for (int l = 0; l < L_; ++l) {
    layernorm_kernel<<<M_, 256, 0, stream>>>(x, ln1_s + l * D_, ln1_b + l * D_, h);
    cvt4_kernel<<<2048, 256, 0, stream>>>(
        qkv_w + (size_t)l * 3 * D_ * D_, proj_w + (size_t)l * D_ * D_,
        fc1_w + (size_t)l * FF_ * D_, fc2_w + (size_t)l * D_ * FF_,
        wq, wp, w1, w2,
        3 * D_ * D_ / 4, D_ * D_ / 4, FF_ * D_ / 4, D_ * FF_ / 4);
    gemm_mfma<false, false, true><<<dim3(24 * 16, 1), 256, 0, stream>>>(
        h, wq, nullptr, qkvb, M_, 3 * D_, D_, D_, 3 * D_, 0, 24);
    attn_mfma_kernel<<<dim3(16, H_, B_), 256, 0, stream>>>(qkvb, attnb);
    gemm_mfma<false, false, false><<<dim3(8 * 16, 2), 256, 0, stream>>>(
        attnb, wp, nullptr, part0, M_, D_, 512, D_, D_, (size_t)M_ * D_, 8);
    reduce2_kernel<<<2048, 256, 0, stream>>>(part0, part1, proj_b + l * D_, x, total4);
    layernorm_kernel<<<M_, 256, 0, stream>>>(x, ln2_s + l * D_, ln2_b + l * D_, h);
    gemm_mfma<true, true, true><<<dim3(32 * 16, 1), 256, 0, stream>>>(
        h, w1, fc1_b + l * FF_, ff, M_, FF_, D_, D_, FF_, 0, 32);
    gemm_mfma<false, false, false><<<dim3(8 * 16, 2), 256, 0, stream>>>(
        ff, w2, nullptr, part0, M_, D_, 2048, FF_, D_, (size_t)M_ * D_, 8);
    reduce2_kernel<<<2048, 256, 0, stream>>>(part0, part1, fc2_b + l * D_, x, total4);
  }
  layernorm_kernel<<<M_, 256, 0, stream>>>(x, lnf_s, lnf_b, h);

  // head GEMM in 8192-row chunks of W (16 MiB bf16 per chunk in wq..w1)
  for (int c0 = 0; c0 < V_; c0 += 8192) {
    int nc = V_ - c0 < 8192 ? V_ - c0 : 8192;
    cvt(head_w + (size_t)c0 * D_, wq, (size_t)nc * D_, stream);
    int nbx = (nc + BN - 1) / BN, nby = M_ / BM;
    gemm_mfma<true, false, false><<<dim3(nbx * nby, 1), 256, 0, stream>>>(
        h, wq, head_b + c0, out + c0, M_, nc, D_, D_, V_, 0, nbx);
  }
}

// Round 5
// 1884.395 us; speedup vs baseline: 8.9293x; 1.0760x over previous
//
#include <hip/hip_runtime.h>
#include <hip/hip_bf16.h>
#include <math.h>

#define B_  2
#define S_  1024
#define D_  1024
#define H_  16
#define HD_ 64
#define L_  8
#define FF_ 4096
#define V_  50257
#define M_  (B_ * S_)     // 2048 token rows
#define EPS_ 1e-5f

typedef __attribute__((ext_vector_type(8))) short short8;   // 8 bf16 (4 VGPRs)
typedef __attribute__((ext_vector_type(4))) float f32x4;    // MFMA accum

__device__ __forceinline__ unsigned short f2bf(float f) {
  union { float f; uint32_t u; } c; c.f = f;
  uint32_t r = (c.u + 0x7FFFu + ((c.u >> 16) & 1u)) >> 16;  // RNE
  return (unsigned short)r;
}
__device__ __forceinline__ void gll16(const unsigned short* g, unsigned short* lds) {
  __builtin_amdgcn_global_load_lds(
      (const __attribute__((address_space(1))) void*)g,
      (__attribute__((address_space(3))) void*)lds, 16, 0, 0);
}

// ---------------------------------------------------------------- embed (fp32 x)
__global__ __launch_bounds__(256) void embed_kernel(
    const int* __restrict__ idx, const float* __restrict__ tok,
    const float* __restrict__ pos, float* __restrict__ x) {
  int i = blockIdx.x * 256 + threadIdx.x;
  int m = i >> 8;
  int d4 = i & 255;
  int s = m & (S_ - 1);
  int t = idx[m];
  float4 tv = ((const float4*)(tok + (size_t)t * D_))[d4];
  float4 pv = ((const float4*)(pos + (size_t)s * D_))[d4];
  float4 o;
  o.x = tv.x + pv.x; o.y = tv.y + pv.y; o.z = tv.z + pv.z; o.w = tv.w + pv.w;
  ((float4*)(x + (size_t)m * D_))[d4] = o;
}

// ---------------------------------------------------------------- f32 -> bf16 (single)
__global__ __launch_bounds__(256) void cvt_bf16_kernel(
    const float* __restrict__ in, unsigned short* __restrict__ out, int n4) {
  int i = blockIdx.x * 256 + threadIdx.x;
  int stride = gridDim.x * 256;
  for (; i < n4; i += stride) {
    float4 v = ((const float4*)in)[i];
    ushort4 o;
    o.x = f2bf(v.x); o.y = f2bf(v.y); o.z = f2bf(v.z); o.w = f2bf(v.w);
    ((ushort4*)out)[i] = o;
  }
}

// ---------------------------------------------------------------- f32 -> bf16 (4 segments)
__global__ __launch_bounds__(256) void cvt4_kernel(
    const float* __restrict__ s0, const float* __restrict__ s1,
    const float* __restrict__ s2, const float* __restrict__ s3,
    unsigned short* __restrict__ d0, unsigned short* __restrict__ d1,
    unsigned short* __restrict__ d2, unsigned short* __restrict__ d3,
    int n0, int n1, int n2, int n3) {          // float4 units
  int total = n0 + n1 + n2 + n3;
  for (int i = blockIdx.x * 256 + threadIdx.x; i < total; i += gridDim.x * 256) {
    const float* s; unsigned short* d; int j = i;
    if (j < n0)              { s = s0; d = d0; }
    else if ((j -= n0) < n1) { s = s1; d = d1; }
    else if ((j -= n1) < n2) { s = s2; d = d2; }
    else                     { j -= n2; s = s3; d = d3; }
    float4 v = ((const float4*)s)[j];
    ushort4 o;
    o.x = f2bf(v.x); o.y = f2bf(v.y); o.z = f2bf(v.z); o.w = f2bf(v.w);
    ((ushort4*)d)[j] = o;
  }
}

// ---------------------------------------------------------------- block reduction
__device__ __forceinline__ float block_sum256(float v, float* red) {
  #pragma unroll
  for (int o = 32; o > 0; o >>= 1) v += __shfl_xor(v, o);
  int w = threadIdx.x >> 6;
  __syncthreads();
  if ((threadIdx.x & 63) == 0) red[w] = v;
  __syncthreads();
  return red[0] + red[1] + red[2] + red[3];
}

// ---------------------------------------------------------------- layernorm (f32 in, bf16 out)
__global__ __launch_bounds__(256) void layernorm_kernel(
    const float* __restrict__ x, const float* __restrict__ sc,
    const float* __restrict__ bi, unsigned short* __restrict__ out) {
  __shared__ float red[4];
  int row = blockIdx.x;
  float4 v = ((const float4*)(x + (size_t)row * D_))[threadIdx.x];
  float sum = block_sum256(v.x + v.y + v.z + v.w, red);
  float mu = sum * (1.0f / D_);
  float dx = v.x - mu, dy = v.y - mu, dz = v.z - mu, dw = v.w - mu;
  float sq = block_sum256(dx*dx + dy*dy + dz*dz + dw*dw, red);
  float r = rsqrtf(sq * (1.0f / D_) + EPS_);
  int c = threadIdx.x * 4;
  float4 s4 = *(const float4*)(sc + c);
  float4 b4 = *(const float4*)(bi + c);
  ushort4 o;
  o.x = f2bf(dx * r * s4.x + b4.x);
  o.y = f2bf(dy * r * s4.y + b4.y);
  o.z = f2bf(dz * r * s4.z + b4.z);
  o.w = f2bf(dw * r * s4.w + b4.w);
  ((ushort4*)(out + (size_t)row * D_))[threadIdx.x] = o;
}

// ---------------------------------------------------------------- split-K(4) reduce + residual + LN
// x[row] += bias + sum_z parts[z]; h[row] = LN(x[row]) in bf16. One block/row.
__global__ __launch_bounds__(256) void reduce_ln_kernel(
    const float* __restrict__ parts, const float* __restrict__ bias,
    float* __restrict__ x, const float* __restrict__ sc,
    const float* __restrict__ bi, unsigned short* __restrict__ h) {
  __shared__ float red[4];
  int row = blockIdx.x;
  int i = row * 256 + threadIdx.x;                 // float4 index into [M,D]
  float4 v = ((const float4*)x)[i];
  float4 bb = ((const float4*)bias)[threadIdx.x];  // N = 1024
  v.x += bb.x; v.y += bb.y; v.z += bb.z; v.w += bb.w;
  #pragma unroll
  for (int z = 0; z < 4; ++z) {
    float4 p = ((const float4*)(parts + (size_t)z * M_ * D_))[i];
    v.x += p.x; v.y += p.y; v.z += p.z; v.w += p.w;
  }
  ((float4*)x)[i] = v;
  float sum = block_sum256(v.x + v.y + v.z + v.w, red);
  float mu = sum * (1.0f / D_);
  float dx = v.x - mu, dy = v.y - mu, dz = v.z - mu, dw = v.w - mu;
  float sq = block_sum256(dx*dx + dy*dy + dz*dz + dw*dw, red);
  float r = rsqrtf(sq * (1.0f / D_) + EPS_);
  int c = threadIdx.x * 4;
  float4 s4 = *(const float4*)(sc + c);
  float4 b4 = *(const float4*)(bi + c);
  ushort4 o;
  o.x = f2bf(dx * r * s4.x + b4.x);
  o.y = f2bf(dy * r * s4.y + b4.y);
  o.z = f2bf(dz * r * s4.z + b4.z);
  o.w = f2bf(dw * r * s4.w + b4.w);
  ((ushort4*)(h + (size_t)row * D_))[threadIdx.x] = o;
}

// ---------------------------------------------------------------- MFMA GEMM
// C[M,N] = A[M,Koff:Koff+K] * W[N,Koff:Koff+K]^T (+bias)(+relu), fp32 accum.
// blockIdx.y = K-split index z; Koff = z*K; output advanced by z*zstride elems.
#define BM 128
#define BN 128
#define BKg 64

template<bool BIAS, bool RELU, bool OUTBF16>
__global__ __launch_bounds__(256) void gemm_mfma(
    const unsigned short* __restrict__ A, const unsigned short* __restrict__ W,
    const float* __restrict__ bias, void* __restrict__ Cout,
    int M, int N, int K, int lda, int ldc, size_t zstride, int nbx) {
  __shared__ unsigned short As[BM * BKg];
  __shared__ unsigned short Bs[BN * BKg];

  // bijective XCD-aware swizzle (m204)
  int nwg = gridDim.x;
  int bid = blockIdx.x;
  int q = nwg >> 3, r = nwg & 7;
  int xcd = bid & 7, sub = bid >> 3;
  int swz = (xcd < r ? xcd * (q + 1) : r * (q + 1) + (xcd - r) * q) + sub;
  int by = swz / nbx, bx = swz % nbx;
  int bm = by * BM, bn = bx * BN;

  const size_t Koff = (size_t)blockIdx.y * K;
  const unsigned short* Ab = A + Koff;
  const unsigned short* Wb = W + Koff;

  const int tid = threadIdx.x;
  const int l = tid & 63, w = tid >> 6;
  const int wm = (w >> 1) * 64, wn = (w & 1) * 64;
  const int lr = l >> 3;            // row within 8-row chunk
  const int lc = (l & 7) << 3;      // col (8 bf16 = 16B)

  const unsigned short* asrc[4];
  const unsigned short* bsrc[4];
  unsigned short* adst[4];
  unsigned short* bdst[4];
  #pragma unroll
  for (int i = 0; i < 4; ++i) {
    int rowa = i * 32 + w * 8;                       // wave-uniform chunk base
    asrc[i] = Ab + (size_t)(bm + rowa + lr) * lda + lc;
    adst[i] = As + rowa * BKg;
    int gn = bn + rowa + lr; if (gn >= N) gn = N - 1;
    bsrc[i] = Wb + (size_t)gn * lda + lc;
    bdst[i] = Bs + rowa * BKg;
  }

  f32x4 acc[4][4] = {};
  for (int k0 = 0; k0 < K; k0 += BKg) {
    __syncthreads();
    #pragma unroll
    for (int i = 0; i < 4; ++i) {
      gll16(asrc[i] + k0, adst[i]);
      gll16(bsrc[i] + k0, bdst[i]);
    }
    __syncthreads();
    short8 af[2][4], bfr[2][4];
    #pragma unroll
    for (int ks = 0; ks < 2; ++ks)
      #pragma unroll
      for (int i = 0; i < 4; ++i) {
        af[ks][i]  = *(const short8*)(As + (wm + i * 16 + (l & 15)) * BKg + ks * 32 + (l >> 4) * 8);
        bfr[ks][i] = *(const short8*)(Bs + (wn + i * 16 + (l & 15)) * BKg + ks * 32 + (l >> 4) * 8);
      }
    #pragma unroll
    for (int ks = 0; ks < 2; ++ks)
      #pragma unroll
      for (int i = 0; i < 4; ++i)
        #pragma unroll
        for (int j = 0; j < 4; ++j)
          acc[i][j] = __builtin_amdgcn_mfma_f32_16x16x32_bf16(af[ks][i], bfr[ks][j], acc[i][j], 0, 0, 0);
  }

  const size_t zoff = (size_t)blockIdx.y * zstride;
  const int er = (l >> 4) * 4;
  const int ec = l & 15;
  #pragma unroll
  for (int j = 0; j < 4; ++j) {
    int col = bn + wn + j * 16 + ec;
    if (col < N) {
      float bv = BIAS ? bias[col] : 0.f;
      #pragma unroll
      for (int i = 0; i < 4; ++i) {
        #pragma unroll
        for (int rr = 0; rr < 4; ++rr) {
          int row = bm + wm + i * 16 + er + rr;
          float v = acc[i][j][rr] + bv;
          if (RELU) v = fmaxf(v, 0.f);
          if (OUTBF16) ((unsigned short*)Cout + zoff)[(size_t)row * ldc + col] = f2bf(v);
          else         ((float*)Cout + zoff)[(size_t)row * ldc + col] = v;
        }
      }
    }
  }
}

// ---------------------------------------------------------------- MFMA flash attention
// Grid (16, H, B): 512 blocks. KVBLK=128 (halves barriers/stages vs 64).
// tile = b ? x : 15-x: co-resident block pair sums to ~9 steps (causal balance).
// T14 reg-prefetch of next KV block; T5 setprio around MFMA clusters.
// Steps per tile: nt = (q0+191)>>7 <= 8, so all loads stay in [0, S).
__global__ __launch_bounds__(256) void attn_mfma_kernel(
    const unsigned short* __restrict__ qkv, unsigned short* __restrict__ out) {
  __shared__ unsigned short Kl[128 * 72];
  __shared__ unsigned short Vt[64 * 136];         // Vt[d][k], k < 128
  __shared__ unsigned short Pl[4 * 16 * 136];     // per-wave P[16][136]
  const int h = blockIdx.y, b = blockIdx.z;
  const int tile = b ? blockIdx.x : (15 - blockIdx.x);
  const int q0 = tile * 64;
  const int nt = (q0 + 191) >> 7;
  const int tid = threadIdx.x;
  const int l = tid & 63, wid = tid >> 6;
  const int g = l >> 4, m15 = l & 15;
  const size_t rs = 3 * D_;                        // qkv row stride
  const unsigned short* base = qkv + (size_t)(b * S_) * rs + h * (3 * HD_);
  const int sd = wid * 16;                         // staged d-range [sd, sd+16)
  unsigned short* Pw = Pl + wid * 16 * 136;

  // Q fragments (A-operand): row m15, k = g*8 (+32)
  const unsigned short* qp = base + (size_t)(q0 + wid * 16 + m15) * rs + g * 8;
  short8 qf0 = *(const short8*)(qp);
  short8 qf1 = *(const short8*)(qp + 32);
  f32x4 acc_o[4] = {};
  float mrun[4] = {-INFINITY, -INFINITY, -INFINITY, -INFINITY};
  float ssum[4] = {0.f, 0.f, 0.f, 0.f};

  // prefetch KV block 0: rows l and 64+l, cols [sd, sd+16)
  short8 kA0, kA1, kB0, kB1, vA0, vA1, vB0, vB1;
  {
    const unsigned short* r0 = base + (size_t)l * rs + HD_ + sd;
    const unsigned short* r1 = r0 + 64 * rs;
    kA0 = *(const short8*)(r0);       kA1 = *(const short8*)(r0 + 8);
    vA0 = *(const short8*)(r0 + HD_); vA1 = *(const short8*)(r0 + HD_ + 8);
    kB0 = *(const short8*)(r1);       kB1 = *(const short8*)(r1 + 8);
    vB0 = *(const short8*)(r1 + HD_); vB1 = *(const short8*)(r1 + HD_ + 8);
  }

  for (int kt = 0; kt < nt; ++kt) {
    const int k128 = kt << 7;
    __syncthreads();                               // prior LDS reads done
    *(short8*)(Kl + l * 72 + sd) = kA0;
    *(short8*)(Kl + l * 72 + sd + 8) = kA1;
    *(short8*)(Kl + (64 + l) * 72 + sd) = kB0;
    *(short8*)(Kl + (64 + l) * 72 + sd + 8) = kB1;
    #pragma unroll
    for (int e = 0; e < 8; ++e) {
      Vt[(sd + e) * 136 + l] = (unsigned short)vA0[e];
      Vt[(sd + 8 + e) * 136 + l] = (unsigned short)vA1[e];
      Vt[(sd + e) * 136 + 64 + l] = (unsigned short)vB0[e];
      Vt[(sd + 8 + e) * 136 + 64 + l] = (unsigned short)vB1[e];
    }
    __syncthreads();
    if (kt + 1 < nt) {                             // T14: issue next-block loads
      const unsigned short* r0 = base + (size_t)(k128 + 128 + l) * rs + HD_ + sd;
      const unsigned short* r1 = r0 + 64 * rs;
      kA0 = *(const short8*)(r0);       kA1 = *(const short8*)(r0 + 8);
      vA0 = *(const short8*)(r0 + HD_); vA1 = *(const short8*)(r0 + HD_ + 8);
      kB0 = *(const short8*)(r1);       kB1 = *(const short8*)(r1 + 8);
      vB0 = *(const short8*)(r1 + HD_); vB1 = *(const short8*)(r1 + HD_ + 8);
    }

    // QK^T: S[16q x 128k] per wave
    f32x4 sc8[8] = {};
    __builtin_amdgcn_s_setprio(1);
    #pragma unroll
    for (int j = 0; j < 8; ++j) {
      short8 kf0 = *(const short8*)(Kl + (j * 16 + m15) * 72 + g * 8);
      short8 kf1 = *(const short8*)(Kl + (j * 16 + m15) * 72 + 32 + g * 8);
      sc8[j] = __builtin_amdgcn_mfma_f32_16x16x32_bf16(qf0, kf0, sc8[j], 0, 0, 0);
      sc8[j] = __builtin_amdgcn_mfma_f32_16x16x32_bf16(qf1, kf1, sc8[j], 0, 0, 0);
    }
    __builtin_amdgcn_s_setprio(0);

    const bool lastt = (kt == nt - 1);             // interior steps: cols < q0
    #pragma unroll
    for (int rr = 0; rr < 4; ++rr) {
      const int qrow = q0 + wid * 16 + g * 4 + rr;
      float sv[8];
      #pragma unroll
      for (int j = 0; j < 8; ++j) {
        sv[j] = sc8[j][rr] * 0.125f;
        if (lastt && (k128 + j * 16 + m15 > qrow)) sv[j] = -1e30f;
      }
      float mx = sv[0];
      #pragma unroll
      for (int j = 1; j < 8; ++j) mx = fmaxf(mx, sv[j]);
      mx = fmaxf(mx, __shfl_xor(mx, 1));
      mx = fmaxf(mx, __shfl_xor(mx, 2));
      mx = fmaxf(mx, __shfl_xor(mx, 4));
      mx = fmaxf(mx, __shfl_xor(mx, 8));
      float mn = fmaxf(mrun[rr], mx);
      float corr = __expf(mrun[rr] - mn);
      mrun[rr] = mn;
      float ts = 0.f;
      #pragma unroll
      for (int j = 0; j < 8; ++j) {
        float p = __expf(sv[j] - mn);
        ts += p;
        Pw[(g * 4 + rr) * 136 + j * 16 + m15] = f2bf(p);
      }
      ts += __shfl_xor(ts, 1); ts += __shfl_xor(ts, 2);
      ts += __shfl_xor(ts, 4); ts += __shfl_xor(ts, 8);
      ssum[rr] = ssum[rr] * corr + ts;
      #pragma unroll
      for (int j = 0; j < 4; ++j) acc_o[j][rr] *= corr;
    }

    // PV: O[16q x 64d] += P[16q x 128k] * V[128k x 64d]
    short8 pa[4];
    #pragma unroll
    for (int ks = 0; ks < 4; ++ks)
      pa[ks] = *(const short8*)(Pw + m15 * 136 + ks * 32 + g * 8);
    __builtin_amdgcn_s_setprio(1);
    #pragma unroll
    for (int j = 0; j < 4; ++j) {
      #pragma unroll
      for (int ks = 0; ks < 4; ++ks) {
        short8 vb = *(const short8*)(Vt + (j * 16 + m15) * 136 + ks * 32 + g * 8);
        acc_o[j] = __builtin_amdgcn_mfma_f32_16x16x32_bf16(pa[ks], vb, acc_o[j], 0, 0, 0);
      }
    }
    __builtin_amdgcn_s_setprio(0);
  }

  #pragma unroll
  for (int rr = 0; rr < 4; ++rr) {
    const int qrow = q0 + wid * 16 + g * 4 + rr;
    float inv = 1.0f / ssum[rr];
    #pragma unroll
    for (int j = 0; j < 4; ++j)
      out[(size_t)(b * S_ + qrow) * D_ + h * HD_ + j * 16 + m15] =
          f2bf(acc_o[j][rr] * inv);
  }
}

// ---------------------------------------------------------------- launch
static inline void cvt(const float* src, unsigned short* dst, size_t n, hipStream_t s) {
  int n4 = (int)(n / 4);
  int blocks = (n4 + 255) / 256;
  if (blocks > 2048) blocks = 2048;
  cvt_bf16_kernel<<<blocks, 256, 0, s>>>(src, dst, n4);
}

extern "C" void kernel_launch(void* const* d_in, const int* in_sizes, int n_in,
                              void* d_out, int out_size, void* d_ws, size_t ws_size,
                              hipStream_t stream) {
  const int*   idx    = (const int*)d_in[0];
  const float* tok    = (const float*)d_in[1];
  const float* pos    = (const float*)d_in[2];
  const float* qkv_w  = (const float*)d_in[3];
  const float* proj_w = (const float*)d_in[4];
  const float* proj_b = (const float*)d_in[5];
  const float* ln1_s  = (const float*)d_in[6];
  const float* ln1_b  = (const float*)d_in[7];
  const float* fc1_w  = (const float*)d_in[8];
  const float* fc1_b  = (const float*)d_in[9];
  const float* fc2_w  = (const float*)d_in[10];
  const float* fc2_b  = (const float*)d_in[11];
  const float* ln2_s  = (const float*)d_in[12];
  const float* ln2_b  = (const float*)d_in[13];
  const float* lnf_s  = (const float*)d_in[14];
  const float* lnf_b  = (const float*)d_in[15];
  const float* head_w = (const float*)d_in[16];
  const float* head_b = (const float*)d_in[17];
  float* out = (float*)d_out;

  // ws layout (MiB offsets), ws_size ~1.6 GB per fill evidence:
  // x@0(8,f32) h@8(4) qkvb@12(12) attnb@24(4) ff@28(16)
  // wq@44(6) wp@50(2) w1@52(8) w2@60(8) parts@68(32,f32) headw@100(16.8)
  char* wsb = (char*)d_ws;
  float*          x      = (float*)(wsb);
  unsigned short* h      = (unsigned short*)(wsb + (8u << 20));
  unsigned short* qkvb   = (unsigned short*)(wsb + (12u << 20));
  unsigned short* attnb  = (unsigned short*)(wsb + (24u << 20));
  unsigned short* ff     = (unsigned short*)(wsb + (28u << 20));
  unsigned short* wq     = (unsigned short*)(wsb + (44u << 20));
  unsigned short* wp     = (unsigned short*)(wsb + (50u << 20));
  unsigned short* w1     = (unsigned short*)(wsb + (52u << 20));
  unsigned short* w2     = (unsigned short*)(wsb + (60u << 20));
  float*          parts  = (float*)(wsb + (68u << 20));
  unsigned short* hw     = (unsigned short*)(wsb + (100u << 20));

  embed_kernel<<<M_ * D_ / 4 / 256, 256, 0, stream>>>(idx, tok, pos, x);
  layernorm_kernel<<<M_, 256, 0, stream>>>(x, ln1_s, ln1_b, h);

  for (int l = 0; l < L_; ++l) {
    cvt4_kernel<<<2048, 256, 0, stream>>>(
        qkv_w + (size_t)l * 3 * D_ * D_, proj_w + (size_t)l * D_ * D_,
        fc1_w + (size_t)l * FF_ * D_, fc2_w + (size_t)l * D_ * FF_,
        wq, wp, w1, w2,
        3 * D_ * D_ / 4, D_ * D_ / 4, FF_ * D_ / 4, D_ * FF_ / 4);
    gemm_mfma<false, false, true><<<dim3(24 * 16, 1), 256, 0, stream>>>(
        h, wq, nullptr, qkvb, M_, 3 * D_, D_, D_, 3 * D_, 0, 24);
    attn_mfma_kernel<<<dim3(16, H_, B_), 256, 0, stream>>>(qkvb, attnb);
    gemm_mfma<false, false, false><<<dim3(8 * 16, 4), 256, 0, stream>>>(
        attnb, wp, nullptr, parts, M_, D_, 256, D_, D_, (size_t)M_ * D_, 8);
    reduce_ln_kernel<<<M_, 256, 0, stream>>>(
        parts, proj_b + l * D_, x, ln2_s + l * D_, ln2_b + l * D_, h);
    gemm_mfma<true, true, true><<<dim3(32 * 16, 1), 256, 0, stream>>>(
        h, w1, fc1_b + l * FF_, ff, M_, FF_, D_, D_, FF_, 0, 32);
    gemm_mfma<false, false, false><<<dim3(8 * 16, 4), 256, 0, stream>>>(
        ff, w2, nullptr, parts, M_, D_, 1024, FF_, D_, (size_t)M_ * D_, 8);
    const float* ns = (l == L_ - 1) ? lnf_s : ln1_s + (l + 1) * D_;
    const float* nb = (l == L_ - 1) ? lnf_b : ln1_b + (l + 1) * D_;
    reduce_ln_kernel<<<M_, 256, 0, stream>>>(
        parts, fc2_b + l * D_, x, ns, nb, h);
  }

  // head GEMM in 8192-row chunks of W
  for (int c0 = 0; c0 < V_; c0 += 8192) {
    int nc = V_ - c0 < 8192 ? V_ - c0 : 8192;
    cvt(head_w + (size_t)c0 * D_, hw, (size_t)nc * D_, stream);
    int nbx = (nc + BN - 1) / BN, nby = M_ / BM;
    gemm_mfma<true, false, false><<<dim3(nbx * nby, 1), 256, 0, stream>>>(
        h, hw, head_b + c0, out + c0, M_, nc, D_, D_, V_, 0, nbx);
  }
}